// Round 11
// baseline (315.759 us; speedup 1.0000x reference)
//
#include <hip/hip_runtime.h>

#define EPS 1e-7f
#define CCH 42
#define NCON 8

typedef float v4f __attribute__((ext_vector_type(4)));
typedef float v2f __attribute__((ext_vector_type(2)));

// ---------------------------------------------------------------------------
// Per-channel MLP (dims NIN -> 5 -> 4 -> 4 -> 3) + 3-way softmax.
// `c` is wave-uniform, so weight/bias loads compile to s_load and FMAs take
// the weight operand from SGPRs.
// ---------------------------------------------------------------------------
template<int NIN>
__device__ __forceinline__ void mlp_softmax3(
    const float x[NIN], int c,
    const float* __restrict__ W0, const float* __restrict__ b0,
    const float* __restrict__ W1, const float* __restrict__ b1,
    const float* __restrict__ W2, const float* __restrict__ b2,
    const float* __restrict__ W3, const float* __restrict__ b3,
    float o[3])
{
    float h0[5];
#pragma unroll
    for (int j = 0; j < 5; ++j) {
        const float* w = W0 + (c * 5 + j) * NIN;
        float a = b0[c * 5 + j];
#pragma unroll
        for (int i = 0; i < NIN; ++i) a = fmaf(x[i], w[i], a);
        h0[j] = fmaxf(a, 0.0f);
    }
    float h1[4];
#pragma unroll
    for (int j = 0; j < 4; ++j) {
        const float* w = W1 + (c * 4 + j) * 5;
        float a = b1[c * 4 + j];
#pragma unroll
        for (int i = 0; i < 5; ++i) a = fmaf(h0[i], w[i], a);
        h1[j] = fmaxf(a, 0.0f);
    }
    float h2[4];
#pragma unroll
    for (int j = 0; j < 4; ++j) {
        const float* w = W2 + (c * 4 + j) * 4;
        float a = b2[c * 4 + j];
#pragma unroll
        for (int i = 0; i < 4; ++i) a = fmaf(h1[i], w[i], a);
        h2[j] = fmaxf(a, 0.0f);
    }
    float lg[3];
#pragma unroll
    for (int j = 0; j < 3; ++j) {
        const float* w = W3 + (c * 3 + j) * 4;
        float a = b3[c * 3 + j];
#pragma unroll
        for (int i = 0; i < 4; ++i) a = fmaf(h2[i], w[i], a);
        lg[j] = a;
    }
    float m = fmaxf(fmaxf(lg[0], lg[1]), lg[2]);
    float e0 = __expf(lg[0] - m);
    float e1 = __expf(lg[1] - m);
    float e2 = __expf(lg[2] - m);
    float r = __fdividef(1.0f, e0 + e1 + e2);
    o[0] = e0 * r;
    o[1] = e1 * r;
    o[2] = e2 * r;
}

// Phase C: consume prefetched tau regs -> 2 exps -> PLAIN stores (through L2;
// fill kernels prove plain stores sustain 6.7+ TB/s vs suspected nt throttle).
__device__ __forceinline__ void phase_c(
    const v4f ta[4], const v4f tb[4],
    const float* __restrict__ mu_direct, const float* __restrict__ mu_diffuse,
    float* __restrict__ out, size_t nctot, int base_e, int per, int tid)
{
#pragma unroll
    for (int it = 0; it < 4; ++it) {
        int off = it * 384 + tid;
        if (off < per) {
            int e = base_e + off;
            v4f a = ta[it];
            v4f b = tb[it];
            float s = ((a.x + a.y) + (a.z + a.w)) + ((b.x + b.y) + (b.z + b.w));
            int nn = e / CCH;
            float md = mu_direct[nn] + EPS;
            float mf = mu_diffuse[nn] + EPS;
            out[e] = __expf(__fdividef(-s, md));
            out[nctot + e] = __expf(__fdividef(-s, mf));
        }
    }
}

// ---------------------------------------------------------------------------
// Fused kernel (R7 structure, nt-store ablation). grid = (N/64, 2).
// Block = 384 thr / 6 waves, 64 samples, one output slice + 1344-elem tau chunk.
//   Issue order (vmcnt in-order): cons+mu FIRST, then 8 tau nt-loads (read-
//   once, keep out of L2), so phase A waits a counted vmcnt and tau stays in
//   flight under the MLP VALU phase.
//   ALL STORES PLAIN (through L2 write-combining) — the single change vs R7.
// ---------------------------------------------------------------------------
__global__ __launch_bounds__(384, 6) void k_fused(
    const float* __restrict__ tau,
    const float* __restrict__ mu_direct,
    const float* __restrict__ mu_diffuse,
    const float* __restrict__ cons,
    const float* __restrict__ Wd0, const float* __restrict__ bd0,
    const float* __restrict__ Wf0, const float* __restrict__ bf0,
    const float* __restrict__ Wd1, const float* __restrict__ bd1,
    const float* __restrict__ Wf1, const float* __restrict__ bf1,
    const float* __restrict__ Wd2, const float* __restrict__ bd2,
    const float* __restrict__ Wf2, const float* __restrict__ bf2,
    const float* __restrict__ Wd3, const float* __restrict__ bd3,
    const float* __restrict__ Wf3, const float* __restrict__ bf3,
    float* __restrict__ out, int N)
{
    __shared__ float es[64 * 127];
    const int tid  = threadIdx.x;
    const int lane = tid & 63;
    const int wave = tid >> 6;
    const int n0   = blockIdx.x * 64;
    const int n    = n0 + lane;
    const bool direct = (blockIdx.y == 0);
    const size_t nctot = (size_t)N * CCH;

    // ---- Issue the phase-A inputs FIRST (oldest in vmcnt order) ----
    float4 c0 = *(const float4*)(cons + (size_t)n * NCON);
    float4 c1 = *(const float4*)(cons + (size_t)n * NCON + 4);
    float mu  = direct ? mu_direct[n] : 0.0f;
    __builtin_amdgcn_sched_barrier(0);   // pin: cons/mu issue before tau loads

    // ---- Then issue the tau-chunk nt loads (younger; stay in flight) ----
    const int nblk = gridDim.x * 2;
    const int cid  = blockIdx.y * gridDim.x + blockIdx.x;
    const int per  = (int)(nctot / nblk);        // 1344 for N=524288
    const int base_e = cid * per;
    v4f ta[4], tb[4];
#pragma unroll
    for (int it = 0; it < 4; ++it) {
        int off = it * 384 + tid;
        if (off < per) {
            const v4f* t4 = (const v4f*)tau + ((size_t)base_e + off) * 2;
            ta[it] = __builtin_nontemporal_load(t4);
            tb[it] = __builtin_nontemporal_load(t4 + 1);
        }
    }
    __builtin_amdgcn_sched_barrier(0);   // pin: tau loads issued before phase A

    // ---- Phase A: MLP -> LDS ----
    float x[9] = {c0.x, c0.y, c0.z, c0.w, c1.x, c1.y, c1.z, c1.w, 0.0f};
    if (direct) {
        float inv = __fdividef(1.0f, mu + EPS);
#pragma unroll
        for (int i = 0; i < 8; ++i) x[i] *= inv;
        x[8] = mu;
#pragma unroll 1
        for (int ci = 0; ci < 7; ++ci) {
            int c = __builtin_amdgcn_readfirstlane(wave * 7 + ci);
            float o[3];
            mlp_softmax3<9>(x, c, Wd0, bd0, Wd1, bd1, Wd2, bd2, Wd3, bd3, o);
#pragma unroll
            for (int k = 0; k < 3; ++k) es[lane * 127 + c * 3 + k] = o[k];
        }
    } else {
#pragma unroll 1
        for (int ci = 0; ci < 7; ++ci) {
            int c = __builtin_amdgcn_readfirstlane(wave * 7 + ci);
            float o[3];
            mlp_softmax3<8>(x, c, Wf0, bf0, Wf1, bf1, Wf2, bf2, Wf3, bf3, o);
#pragma unroll
            for (int k = 0; k < 3; ++k) es[lane * 127 + c * 3 + k] = o[k];
        }
    }
    __syncthreads();

    // ---- Phase B: coalesced PLAIN writeout of the 64x126 tile ----
    float* base = out + (direct ? 2 : 5) * nctot + (size_t)n0 * (CCH * 3);
    for (int idx = tid; idx < 64 * 63; idx += 384) {
        int r = idx / 63;
        int q = idx - r * 63;
        v2f v;
        v.x = es[r * 127 + 2 * q];
        v.y = es[r * 127 + 2 * q + 1];
        ((v2f*)base)[idx] = v;
    }

    // ---- Phase C: consume prefetched tau, plain stores ----
    phase_c(ta, tb, mu_direct, mu_diffuse, out, nctot, base_e, per, tid);
}

extern "C" void kernel_launch(void* const* d_in, const int* in_sizes, int n_in,
                              void* d_out, int out_size, void* d_ws, size_t ws_size,
                              hipStream_t stream) {
    const float* tau  = (const float*)d_in[0];
    const float* mud  = (const float*)d_in[1];
    const float* muf  = (const float*)d_in[2];
    const float* cons = (const float*)d_in[3];
    // setup_inputs() dict order: Wd{i}, bd{i}, Wf{i}, bf{i} interleaved per layer.
    const float* Wd0 = (const float*)d_in[4];  const float* bd0 = (const float*)d_in[5];
    const float* Wf0 = (const float*)d_in[6];  const float* bf0 = (const float*)d_in[7];
    const float* Wd1 = (const float*)d_in[8];  const float* bd1 = (const float*)d_in[9];
    const float* Wf1 = (const float*)d_in[10]; const float* bf1 = (const float*)d_in[11];
    const float* Wd2 = (const float*)d_in[12]; const float* bd2 = (const float*)d_in[13];
    const float* Wf2 = (const float*)d_in[14]; const float* bf2 = (const float*)d_in[15];
    const float* Wd3 = (const float*)d_in[16]; const float* bd3 = (const float*)d_in[17];
    const float* Wf3 = (const float*)d_in[18]; const float* bf3 = (const float*)d_in[19];
    float* out = (float*)d_out;

    int N = in_sizes[1];            // mu_direct element count = N
    dim3 grid(N / 64, 2);
    k_fused<<<grid, 384, 0, stream>>>(tau, mud, muf, cons,
                                      Wd0, bd0, Wf0, bf0,
                                      Wd1, bd1, Wf1, bf1,
                                      Wd2, bd2, Wf2, bf2,
                                      Wd3, bd3, Wf3, bf3,
                                      out, N);
}

// Round 12
// 293.091 us; speedup vs baseline: 1.0773x; 1.0773x over previous
//
#include <hip/hip_runtime.h>

#define EPS 1e-7f
#define CCH 42
#define NCON 8

typedef float v4f __attribute__((ext_vector_type(4)));
typedef float v2f __attribute__((ext_vector_type(2)));

// ---------------------------------------------------------------------------
// Per-channel MLP (dims NIN -> 5 -> 4 -> 4 -> 3) + 3-way softmax.
// `c` is wave-uniform, so weight/bias loads compile to s_load and FMAs take
// the weight operand from SGPRs.
// ---------------------------------------------------------------------------
template<int NIN>
__device__ __forceinline__ void mlp_softmax3(
    const float x[NIN], int c,
    const float* __restrict__ W0, const float* __restrict__ b0,
    const float* __restrict__ W1, const float* __restrict__ b1,
    const float* __restrict__ W2, const float* __restrict__ b2,
    const float* __restrict__ W3, const float* __restrict__ b3,
    float o[3])
{
    float h0[5];
#pragma unroll
    for (int j = 0; j < 5; ++j) {
        const float* w = W0 + (c * 5 + j) * NIN;
        float a = b0[c * 5 + j];
#pragma unroll
        for (int i = 0; i < NIN; ++i) a = fmaf(x[i], w[i], a);
        h0[j] = fmaxf(a, 0.0f);
    }
    float h1[4];
#pragma unroll
    for (int j = 0; j < 4; ++j) {
        const float* w = W1 + (c * 4 + j) * 5;
        float a = b1[c * 4 + j];
#pragma unroll
        for (int i = 0; i < 5; ++i) a = fmaf(h0[i], w[i], a);
        h1[j] = fmaxf(a, 0.0f);
    }
    float h2[4];
#pragma unroll
    for (int j = 0; j < 4; ++j) {
        const float* w = W2 + (c * 4 + j) * 4;
        float a = b2[c * 4 + j];
#pragma unroll
        for (int i = 0; i < 4; ++i) a = fmaf(h1[i], w[i], a);
        h2[j] = fmaxf(a, 0.0f);
    }
    float lg[3];
#pragma unroll
    for (int j = 0; j < 3; ++j) {
        const float* w = W3 + (c * 3 + j) * 4;
        float a = b3[c * 3 + j];
#pragma unroll
        for (int i = 0; i < 4; ++i) a = fmaf(h2[i], w[i], a);
        lg[j] = a;
    }
    float m = fmaxf(fmaxf(lg[0], lg[1]), lg[2]);
    float e0 = __expf(lg[0] - m);
    float e1 = __expf(lg[1] - m);
    float e2 = __expf(lg[2] - m);
    float r = __fdividef(1.0f, e0 + e1 + e2);
    o[0] = e0 * r;
    o[1] = e1 * r;
    o[2] = e2 * r;
}

// Phase C: consume prefetched tau regs -> 2 exps -> nt stores.
// All indices static after inlining (#pragma unroll) -- no scratch (rule #20).
__device__ __forceinline__ void phase_c(
    const v4f ta[4], const v4f tb[4],
    const float* __restrict__ mu_direct, const float* __restrict__ mu_diffuse,
    float* __restrict__ out, size_t nctot, int base_e, int per, int tid)
{
#pragma unroll
    for (int it = 0; it < 4; ++it) {
        int off = it * 384 + tid;
        if (off < per) {
            int e = base_e + off;
            v4f a = ta[it];
            v4f b = tb[it];
            float s = ((a.x + a.y) + (a.z + a.w)) + ((b.x + b.y) + (b.z + b.w));
            int nn = e / CCH;
            float md = mu_direct[nn] + EPS;
            float mf = mu_diffuse[nn] + EPS;
            __builtin_nontemporal_store(__expf(__fdividef(-s, md)), out + e);
            __builtin_nontemporal_store(__expf(__fdividef(-s, mf)), out + nctot + e);
        }
    }
}

// ---------------------------------------------------------------------------
// Fused kernel (R7 structure; load-type ablation: PLAIN tau loads through L2,
// nt stores). grid = (N/64, 2). Block = 384 thr / 6 waves, 64 samples, one
// output slice + 1344-elem tau chunk.
//   Issue order (vmcnt in-order): cons+mu FIRST, then 8 tau loads, so phase A
//   waits a counted vmcnt and the tau stream stays in flight under the MLP
//   VALU phase. L2 aggregates the read bursts (m13 copy-BW path); nt stores
//   keep the write-once stream out of L2 (R11 showed plain stores cost +21us).
// ---------------------------------------------------------------------------
__global__ __launch_bounds__(384, 6) void k_fused(
    const float* __restrict__ tau,
    const float* __restrict__ mu_direct,
    const float* __restrict__ mu_diffuse,
    const float* __restrict__ cons,
    const float* __restrict__ Wd0, const float* __restrict__ bd0,
    const float* __restrict__ Wf0, const float* __restrict__ bf0,
    const float* __restrict__ Wd1, const float* __restrict__ bd1,
    const float* __restrict__ Wf1, const float* __restrict__ bf1,
    const float* __restrict__ Wd2, const float* __restrict__ bd2,
    const float* __restrict__ Wf2, const float* __restrict__ bf2,
    const float* __restrict__ Wd3, const float* __restrict__ bd3,
    const float* __restrict__ Wf3, const float* __restrict__ bf3,
    float* __restrict__ out, int N)
{
    __shared__ float es[64 * 127];
    const int tid  = threadIdx.x;
    const int lane = tid & 63;
    const int wave = tid >> 6;
    const int n0   = blockIdx.x * 64;
    const int n    = n0 + lane;
    const bool direct = (blockIdx.y == 0);
    const size_t nctot = (size_t)N * CCH;

    // ---- Issue the phase-A inputs FIRST (oldest in vmcnt order) ----
    float4 c0 = *(const float4*)(cons + (size_t)n * NCON);
    float4 c1 = *(const float4*)(cons + (size_t)n * NCON + 4);
    float mu  = direct ? mu_direct[n] : 0.0f;
    __builtin_amdgcn_sched_barrier(0);   // pin: cons/mu issue before tau loads

    // ---- Then issue the tau-chunk PLAIN loads (younger; stay in flight) ----
    const int nblk = gridDim.x * 2;
    const int cid  = blockIdx.y * gridDim.x + blockIdx.x;
    const int per  = (int)(nctot / nblk);        // 1344 for N=524288
    const int base_e = cid * per;
    v4f ta[4], tb[4];
#pragma unroll
    for (int it = 0; it < 4; ++it) {
        int off = it * 384 + tid;
        if (off < per) {
            const v4f* t4 = (const v4f*)tau + ((size_t)base_e + off) * 2;
            ta[it] = t4[0];
            tb[it] = t4[1];
        }
    }
    __builtin_amdgcn_sched_barrier(0);   // pin: tau loads issued before phase A

    // ---- Phase A: MLP -> LDS ----
    float x[9] = {c0.x, c0.y, c0.z, c0.w, c1.x, c1.y, c1.z, c1.w, 0.0f};
    if (direct) {
        float inv = __fdividef(1.0f, mu + EPS);
#pragma unroll
        for (int i = 0; i < 8; ++i) x[i] *= inv;
        x[8] = mu;
#pragma unroll 1
        for (int ci = 0; ci < 7; ++ci) {
            int c = __builtin_amdgcn_readfirstlane(wave * 7 + ci);
            float o[3];
            mlp_softmax3<9>(x, c, Wd0, bd0, Wd1, bd1, Wd2, bd2, Wd3, bd3, o);
#pragma unroll
            for (int k = 0; k < 3; ++k) es[lane * 127 + c * 3 + k] = o[k];
        }
    } else {
#pragma unroll 1
        for (int ci = 0; ci < 7; ++ci) {
            int c = __builtin_amdgcn_readfirstlane(wave * 7 + ci);
            float o[3];
            mlp_softmax3<8>(x, c, Wf0, bf0, Wf1, bf1, Wf2, bf2, Wf3, bf3, o);
#pragma unroll
            for (int k = 0; k < 3; ++k) es[lane * 127 + c * 3 + k] = o[k];
        }
    }
    __syncthreads();

    // ---- Phase B: coalesced nt writeout of the 64x126 tile ----
    float* base = out + (direct ? 2 : 5) * nctot + (size_t)n0 * (CCH * 3);
    for (int idx = tid; idx < 64 * 63; idx += 384) {
        int r = idx / 63;
        int q = idx - r * 63;
        v2f v;
        v.x = es[r * 127 + 2 * q];
        v.y = es[r * 127 + 2 * q + 1];
        __builtin_nontemporal_store(v, (v2f*)base + idx);
    }

    // ---- Phase C: consume prefetched tau, nt stores ----
    phase_c(ta, tb, mu_direct, mu_diffuse, out, nctot, base_e, per, tid);
}

extern "C" void kernel_launch(void* const* d_in, const int* in_sizes, int n_in,
                              void* d_out, int out_size, void* d_ws, size_t ws_size,
                              hipStream_t stream) {
    const float* tau  = (const float*)d_in[0];
    const float* mud  = (const float*)d_in[1];
    const float* muf  = (const float*)d_in[2];
    const float* cons = (const float*)d_in[3];
    // setup_inputs() dict order: Wd{i}, bd{i}, Wf{i}, bf{i} interleaved per layer.
    const float* Wd0 = (const float*)d_in[4];  const float* bd0 = (const float*)d_in[5];
    const float* Wf0 = (const float*)d_in[6];  const float* bf0 = (const float*)d_in[7];
    const float* Wd1 = (const float*)d_in[8];  const float* bd1 = (const float*)d_in[9];
    const float* Wf1 = (const float*)d_in[10]; const float* bf1 = (const float*)d_in[11];
    const float* Wd2 = (const float*)d_in[12]; const float* bd2 = (const float*)d_in[13];
    const float* Wf2 = (const float*)d_in[14]; const float* bf2 = (const float*)d_in[15];
    const float* Wd3 = (const float*)d_in[16]; const float* bd3 = (const float*)d_in[17];
    const float* Wf3 = (const float*)d_in[18]; const float* bf3 = (const float*)d_in[19];
    float* out = (float*)d_out;

    int N = in_sizes[1];            // mu_direct element count = N
    dim3 grid(N / 64, 2);
    k_fused<<<grid, 384, 0, stream>>>(tau, mud, muf, cons,
                                      Wd0, bd0, Wf0, bf0,
                                      Wd1, bd1, Wf1, bf1,
                                      Wd2, bd2, Wf2, bf2,
                                      Wd3, bd3, Wf3, bf3,
                                      out, N);
}